// Round 9
// baseline (207.575 us; speedup 1.0000x reference)
//
#include <hip/hip_runtime.h>
#include <math.h>

#define NJ 960           // tail columns (global 64..1023)
#define NSRC 896         // tail sources (global 128..1023)
#define NWARM 25

typedef unsigned long long u64;
typedef unsigned int u32;

// ws (u64 idx): RK[896] tag|(rE|rI<<16), CT[960] tag|(cntE|cntI<<16),
//               HD[960] tag|float(hd[j]).  Proven tag protocol (poison-safe).
#define RK_O 0u
#define CT_O 896u
#define HD_O 1856u

#define TAG_RK 0x524B0001u
#define TAG_CT 0x43540001u
#define TAG_HD 0x48440001u

__device__ __forceinline__ void ast(u64* p, u64 v) {
  __hip_atomic_store(p, v, __ATOMIC_RELAXED, __HIP_MEMORY_SCOPE_AGENT);
}
__device__ __forceinline__ u64 ald(const u64* p) {
  return __hip_atomic_load(p, __ATOMIC_RELAXED, __HIP_MEMORY_SCOPE_AGENT);
}
__device__ __forceinline__ u32 poll32(const u64* p, u32 tag) {
  u64 v = ald(p);
  while ((u32)(v >> 32) != tag) { __builtin_amdgcn_s_sleep(8); v = ald(p); }
  return (u32)v;
}

// ONE kernel, grid 256 x 576 (9 waves, 1 block/CU, all resident):
//   waves 0..7 : GEMM over this block's 64 rows (weights generated in-register
//                via the separable exp form -> NO staging barriers)
//   wave 8     : the 25-iter warmup scan, redundantly per block, wave-
//                synchronous (no __syncthreads after the one staging barrier)
//   blocks 0..29 additionally compute the prep slices (tag-published, proven)
// Handoff scan->GEMM is one LDS flag (release/acquire). The 62 us serial
// scan block disappears: every CU runs its own scan under its own GEMM.
__global__ __launch_bounds__(576) void grn_one(
    const float* __restrict__ inp, const float* __restrict__ ident,
    const float* __restrict__ enh, const float* __restrict__ inh,
    const float* __restrict__ beta, const float* __restrict__ delta,
    void* __restrict__ wsv, float* __restrict__ out) {
  // scan arrays transposed: position p lives at S*[p&15][p>>4] so lane l's
  // 16 positions (16l..16l+15) are lane-contiguous per u (4-way-min b64).
  __shared__ float2 SE[16][64];
  __shared__ float2 SI[16][64];
  __shared__ float4 SRCX[NSRC];   // tail-source {e^{+be},e^{-be},e^{+bi},e^{-bi}}
  __shared__ float4 HEK[64];      // head-source exps (GEMM weight gen)
  __shared__ float2 HEI[64];      // head-source raw {e,i}
  __shared__ float At[64][68];    // input tile transposed [col][row]
  __shared__ float bch[NJ];       // base bias, published by scan wave
  __shared__ u32 sflag;

  u64* RK = (u64*)wsv + RK_O;
  u64* CT = (u64*)wsv + CT_O;
  u64* HD = (u64*)wsv + HD_O;

  const int tid = threadIdx.x;
  const float bb = beta[0];
  const float dN = delta[0] / 1024.0f;
  const size_t rowbase = (size_t)blockIdx.x * 64;

  // ---------------- phase 1: stage LDS (all 576 threads) ----------------
  #pragma unroll
  for (int it = 0; it < 2; ++it) {
    int fi = tid + it * 576;
    if (fi < 1024) {
      int r = fi >> 4, c4 = (fi & 15) * 4;
      float4 f4 = *(const float4*)(inp + (rowbase + r) * 64 + c4);
      At[c4 + 0][r] = f4.x; At[c4 + 1][r] = f4.y;
      At[c4 + 2][r] = f4.z; At[c4 + 3][r] = f4.w;
    }
  }
  for (int m = tid; m < NSRC; m += 576) {
    float e = enh[128 + m], iv = inh[128 + m];
    SRCX[m] = make_float4(expf(bb * e), expf(-bb * e),
                          expf(bb * iv), expf(-bb * iv));
  }
  if (tid < 64) {
    float e = enh[tid], iv = inh[tid];
    HEK[tid] = make_float4(expf(bb * e), expf(-bb * e),
                           expf(bb * iv), expf(-bb * iv));
    HEI[tid] = make_float2(e, iv);
  }
  if (tid == 0) sflag = 0;

  // ---------------- prep slices (blocks 0..29, tid<256; proven) ----------
  if (blockIdx.x < 30 && tid < 256) {
    const int g = (int)blockIdx.x * 256 + tid;   // 0..7679
    const int c8 = g & 7;
    if (g < NSRC * 8) {
      int m = g >> 3;
      float myE = enh[128 + m], myI = inh[128 + m];
      int re = 0, ri = 0;
      for (int i = 112 * c8; i < 112 * c8 + 112; ++i) {
        float ev = enh[128 + i], iv = inh[128 + i];
        re += (ev < myE || (ev == myE && i < m)) ? 1 : 0;
        ri += (iv < myI || (iv == myI && i < m)) ? 1 : 0;
      }
      int p = re | (ri << 16);
      p += __shfl_xor(p, 1); p += __shfl_xor(p, 2); p += __shfl_xor(p, 4);
      if (c8 == 0) ast(&RK[m], ((u64)TAG_RK << 32) | (u32)p);
    }
    {
      int j = g >> 3;
      float cj = ident[64 + j];
      int ce = 0, ci = 0;
      for (int i = 112 * c8; i < 112 * c8 + 112; ++i) {
        ce += (enh[128 + i] <= cj) ? 1 : 0;
        ci += (inh[128 + i] <= cj) ? 1 : 0;
      }
      int p = ce | (ci << 16);
      p += __shfl_xor(p, 1); p += __shfl_xor(p, 2); p += __shfl_xor(p, 4);
      if (c8 == 0) ast(&CT[j], ((u64)TAG_CT << 32) | (u32)p);
    }
    {
      int j = g >> 3;
      float cj = ident[64 + j];
      float h = 0.0f;
      for (int k = 8 * c8; k < 8 * c8 + 8; ++k)
        h += expf(-bb * fabsf(enh[k] - cj)) - expf(-bb * fabsf(inh[k] - cj));
      h += __shfl_xor(h, 1); h += __shfl_xor(h, 2); h += __shfl_xor(h, 4);
      if (c8 == 0)
        ast(&HD[j], ((u64)TAG_HD << 32) |
                    (u64)__float_as_uint(dN * h * (1.0f / 1024.0f)));
    }
  }
  __syncthreads();   // the ONLY block-wide barrier

  if (tid >= 512) {
    // ================= scan wave (wave 8), wave-synchronous ================
    __builtin_amdgcn_s_setprio(1);
    const int lane = tid - 512;
    const int c0l = lane * 15;            // owns cols c0l..c0l+14 (960 = 64*15)

    // zero all 1024 scan positions once (scatter rewrites 1..896 every iter;
    // 0 and 897..1023 stay zero: writeback below skips p>896)
    #pragma unroll
    for (int u = 0; u < 16; ++u) {
      SE[u][lane] = make_float2(0.f, 0.f);
      SI[u][lane] = make_float2(0.f, 0.f);
    }

    float fmv[15], fpv[15], hdv[15], y[15];
    int cc[15], rr[15];
    #pragma unroll
    for (int s = 0; s < 15; ++s) {
      float cj = ident[64 + c0l + s];
      fmv[s] = expf(-bb * cj); fpv[s] = expf(bb * cj);
      y[s] = 1.0f / 1024.0f;
      rr[s] = 0;
    }
    #pragma unroll
    for (int s = 0; s < 15; ++s) {
      cc[s] = (int)poll32(&CT[c0l + s], TAG_CT);
      hdv[s] = __uint_as_float(poll32(&HD[c0l + s], TAG_HD));
    }
    #pragma unroll
    for (int s = 0; s < 15; ++s) {
      int c = c0l + s;
      if (c >= 64) rr[s] = (int)poll32(&RK[c - 64], TAG_RK);
    }

    for (int t = 0; t <= NWARM; ++t) {
      // scatter own sources by rank (source m = c-64 has y = y[s], same s)
      #pragma unroll
      for (int s = 0; s < 15; ++s) {
        int c = c0l + s;
        if (c >= 64) {
          float4 X = SRCX[c - 64];
          int qE = (rr[s] & 0xFFFF) + 1;
          int qI = ((rr[s] >> 16) & 0xFFFF) + 1;
          SE[qE & 15][qE >> 4] = make_float2(y[s] * X.x, y[s] * X.y);
          SI[qI & 15][qI >> 4] = make_float2(y[s] * X.z, y[s] * X.w);
        }
      }
      asm volatile("s_waitcnt lgkmcnt(0)" ::: "memory");
      __builtin_amdgcn_sched_barrier(0);

      // pass 1: lane totals over own 16 positions
      float2 tE = make_float2(0.f, 0.f), tI = make_float2(0.f, 0.f);
      #pragma unroll
      for (int u = 0; u < 16; ++u) {
        float2 a = SE[u][lane], b = SI[u][lane];
        tE.x += a.x; tE.y += a.y; tI.x += b.x; tI.y += b.y;
      }
      float4 inc = make_float4(tE.x, tE.y, tI.x, tI.y);
      float4 tot = inc;
      #pragma unroll
      for (int off = 1; off < 64; off <<= 1) {
        float ox = __shfl_up(inc.x, off, 64);
        float oy = __shfl_up(inc.y, off, 64);
        float oz = __shfl_up(inc.z, off, 64);
        float ow = __shfl_up(inc.w, off, 64);
        if (lane >= off) { inc.x += ox; inc.y += oy; inc.z += oz; inc.w += ow; }
      }
      float TEy = __shfl(inc.y, 63, 64);    // prefix totals (zeros past 896)
      float TIy = __shfl(inc.w, 63, 64);
      float2 pe = make_float2(inc.x - tot.x, inc.y - tot.y);   // exclusive base
      float2 pi = make_float2(inc.z - tot.z, inc.w - tot.w);

      // pass 2: re-read + write back inclusive prefix (positions <= 896 only)
      #pragma unroll
      for (int u = 0; u < 16; ++u) {
        float2 a = SE[u][lane], b = SI[u][lane];
        pe.x += a.x; pe.y += a.y; pi.x += b.x; pi.y += b.y;
        if (lane * 16 + u <= NSRC) { SE[u][lane] = pe; SI[u][lane] = pi; }
      }
      asm volatile("s_waitcnt lgkmcnt(0)" ::: "memory");
      __builtin_amdgcn_sched_barrier(0);

      // combine at precomputed counts
      float nv[15]; float psum = 0.0f;
      #pragma unroll
      for (int s = 0; s < 15; ++s) {
        int cE = cc[s] & 0xFFFF, cI = (cc[s] >> 16) & 0xFFFF;
        float2 AE = SE[cE & 15][cE >> 4];
        float2 AI = SI[cI & 15][cI >> 4];
        float dot = fmv[s] * AE.x + fpv[s] * (TEy - AE.y)
                  - fmv[s] * AI.x - fpv[s] * (TIy - AI.y);
        float pre = y[s] + dN * dot;
        if (t < NWARM) {
          nv[s] = fmaxf(pre + hdv[s], 0.0f);
          psum += nv[s];
        } else {
          bch[c0l + s] = pre;
        }
      }
      if (t < NWARM) {
        #pragma unroll
        for (int off = 32; off >= 1; off >>= 1) psum += __shfl_xor(psum, off);
        float invs = (psum > 0.0f) ? 1.0f / psum : 1.0f;
        #pragma unroll
        for (int s = 0; s < 15; ++s) y[s] = nv[s] * invs;
      }
    }
    asm volatile("s_waitcnt lgkmcnt(0)" ::: "memory");
    __hip_atomic_store(&sflag, 1u, __ATOMIC_RELEASE,
                       __HIP_MEMORY_SCOPE_WORKGROUP);
    __builtin_amdgcn_s_setprio(0);
    return;
  }

  // ================= GEMM waves (tid < 512) =================
  const int lane = tid & 63;
  const int wv = tid >> 6;
  const int rw = wv * 8;                    // 8 waves x 8 rows = 64 rows

  float rs[8];
  #pragma unroll
  for (int r = 0; r < 8; ++r) rs[r] = 0.0f;

  float acc0[8][4], acc1[8][4], acc2[8][4], acc3[8][4];

  // weights generated in-register: w = dN*(exp(-b|e_k-c_j|)-exp(-b|i_k-c_j|))
  // via separable form; dN folded into fpd/fmd. No Wl LDS, no barriers.
  auto run_chunk = [&](int c0, float (&acc)[8][4]) {
    float cjv[4], fpd[4], fmd[4];
    #pragma unroll
    for (int u = 0; u < 4; ++u) {
      int j = c0 + lane * 4 + u;
      bool okj = j < NJ;
      float cj = okj ? ident[64 + j] : 0.0f;
      cjv[u] = cj;
      fpd[u] = okj ? dN * expf(bb * cj) : 0.0f;   // masked cols -> w = 0
      fmd[u] = okj ? dN * expf(-bb * cj) : 0.0f;
    }
    #pragma unroll
    for (int r = 0; r < 8; ++r)
      #pragma unroll
      for (int u = 0; u < 4; ++u) acc[r][u] = 0.0f;
    #pragma unroll 4
    for (int kk = 0; kk < 64; ++kk) {
      float2 ei = HEI[kk];                       // broadcast LDS reads
      float4 E = HEK[kk];
      float w[4];
      #pragma unroll
      for (int u = 0; u < 4; ++u) {
        float we = (ei.x >= cjv[u]) ? E.y * fpd[u] : E.x * fmd[u];
        float wi = (ei.y >= cjv[u]) ? E.w * fpd[u] : E.z * fmd[u];
        w[u] = we - wi;
      }
      float4 a0 = *(const float4*)&At[kk][rw];   // broadcast b128
      float4 a1 = *(const float4*)&At[kk][rw + 4];
      float a_[8] = {a0.x, a0.y, a0.z, a0.w, a1.x, a1.y, a1.z, a1.w};
      #pragma unroll
      for (int r = 0; r < 8; ++r)
        #pragma unroll
        for (int u = 0; u < 4; ++u)
          acc[r][u] = fmaf(a_[r], w[u], acc[r][u]);
    }
  };
  auto fold_chunk = [&](int c0, float (&acc)[8][4]) {
    #pragma unroll
    for (int u = 0; u < 4; ++u) {
      int j = c0 + lane * 4 + u;
      float bv = (j < NJ) ? bch[j] : -1.0e30f;   // acc is 0 there -> relu 0
      #pragma unroll
      for (int r = 0; r < 8; ++r)
        rs[r] += fmaxf(acc[r][u] + bv, 0.0f);
    }
  };

  // scan-independent chunks first (hide under the ~28 us scan)
  run_chunk(256, acc1);
  run_chunk(512, acc2);
  run_chunk(768, acc3);

  while (__hip_atomic_load(&sflag, __ATOMIC_ACQUIRE,
                           __HIP_MEMORY_SCOPE_WORKGROUP) == 0u)
    __builtin_amdgcn_s_sleep(16);

  fold_chunk(256, acc1);
  fold_chunk(512, acc2);
  fold_chunk(768, acc3);
  run_chunk(0, acc0);                       // output chunk last: acc live
  fold_chunk(0, acc0);

  #pragma unroll
  for (int r = 0; r < 8; ++r) {
    float v = rs[r];
    #pragma unroll
    for (int off = 32; off >= 1; off >>= 1) v += __shfl_xor(v, off);
    rs[r] = v;
  }
  if (lane < 16) {
    #pragma unroll
    for (int r = 0; r < 8; ++r) {
      float inv = (rs[r] > 0.0f) ? 1.0f / rs[r] : 1.0f;
      float* op = out + (rowbase + rw + r) * 64 + lane * 4;
      float4 o;
      o.x = fmaxf(acc0[r][0] + bch[lane * 4 + 0], 0.0f) * inv;
      o.y = fmaxf(acc0[r][1] + bch[lane * 4 + 1], 0.0f) * inv;
      o.z = fmaxf(acc0[r][2] + bch[lane * 4 + 2], 0.0f) * inv;
      o.w = fmaxf(acc0[r][3] + bch[lane * 4 + 3], 0.0f) * inv;
      *(float4*)op = o;
    }
  }
}

extern "C" void kernel_launch(void* const* d_in, const int* in_sizes, int n_in,
                              void* d_out, int out_size, void* d_ws, size_t ws_size,
                              hipStream_t stream) {
  const float* inp   = (const float*)d_in[0];
  const float* ident = (const float*)d_in[1];
  const float* enh   = (const float*)d_in[2];
  const float* inh   = (const float*)d_in[3];
  const float* beta  = (const float*)d_in[4];
  const float* delta = (const float*)d_in[5];

  hipLaunchKernelGGL(grn_one, dim3(256), dim3(576), 0, stream,
                     inp, ident, enh, inh, beta, delta, d_ws, (float*)d_out);
}

// Round 10
// 185.346 us; speedup vs baseline: 1.1199x; 1.1199x over previous
//
#include <hip/hip_runtime.h>
#include <math.h>

#define NJ 960           // tail columns (global 64..1023)
#define NSRC 896         // tail sources (global 128..1023)
#define NWARM 25

typedef unsigned long long u64;
typedef unsigned int u32;

// ws layout:
//   u64 idx: RK[896] tag|(rE|rI<<16), CT[960] tag|(cntE|cntI<<16),
//            HD[960] tag|float(hd[j])
//   float idx 8192 : Wk[64][960]  (built by front_k blocks 31..60)
//   float idx 69632: base[960]    (plain floats; K1->K2 kernel boundary orders)
#define RK_O 0u
#define CT_O 896u
#define HD_O 1856u
#define WK_F 8192u
#define BASE_F 69632u

#define TAG_RK 0x524B0001u
#define TAG_CT 0x43540001u
#define TAG_HD 0x48440001u

__device__ __forceinline__ void ast(u64* p, u64 v) {
  __hip_atomic_store(p, v, __ATOMIC_RELAXED, __HIP_MEMORY_SCOPE_AGENT);
}
__device__ __forceinline__ u64 ald(const u64* p) {
  return __hip_atomic_load(p, __ATOMIC_RELAXED, __HIP_MEMORY_SCOPE_AGENT);
}
__device__ __forceinline__ u32 poll32(const u64* p, u32 tag) {
  u64 v = ald(p);
  while ((u32)(v >> 32) != tag) { __builtin_amdgcn_s_sleep(8); v = ald(p); }
  return (u32)v;
}

// K1, grid 61 x 256:
//   block 0      : warmup scan on ONE WAVE (R9's proven wave-synchronous scan:
//                  zero barriers; 2.4us/iter 4-wave version was barrier-bound).
//                  Threads 64..255 exit immediately (no barriers in block 0).
//   blocks 1..30 : prep A/B/C (ranks/counts/hd), tag-published (proven)
//   blocks 31..60: part D (Wk table) on separate blocks (proven: keeps the
//                  heavy exp loops off the scan's CU; 80.8 -> 62.1 us lesson)
// (256,1): empirical VGPR cap law 256/w -> 256; scan state ~135 regs, no spill.
__global__ __launch_bounds__(256, 1) void front_k(
    const float* __restrict__ ident, const float* __restrict__ enh,
    const float* __restrict__ inh, const float* __restrict__ beta,
    const float* __restrict__ delta, void* __restrict__ wsv) {
  // scan arrays transposed: position p lives at S*[p&15][p>>4] so lane l owns
  // positions 16l..16l+15 (R9-proven layout).
  __shared__ float2 SE[16][64];
  __shared__ float2 SI[16][64];
  __shared__ float4 SRCX[NSRC];   // tail-source {e^{+be},e^{-be},e^{+bi},e^{-bi}}

  u64* RK = (u64*)wsv + RK_O;
  u64* CT = (u64*)wsv + CT_O;
  u64* HD = (u64*)wsv + HD_O;
  float* Wk = (float*)wsv + WK_F;
  float* base = (float*)wsv + BASE_F;

  const int tid = threadIdx.x;
  const float bb = beta[0];
  const float dN = delta[0] / 1024.0f;

  if (blockIdx.x > 30) {
    // ---------------- part D: Wk table (proven) ----------------
    const int g2 = (int)(blockIdx.x - 31) * 256 + tid;   // 0..7679
    int k = g2 / 120;
    int jb = (g2 % 120) * 8;
    float ek = enh[k], ik = inh[k];
    #pragma unroll
    for (int u = 0; u < 8; ++u) {
      float cj = ident[64 + jb + u];
      Wk[(size_t)k * NJ + jb + u] =
          dN * (expf(-bb * fabsf(ek - cj)) - expf(-bb * fabsf(ik - cj)));
    }
    return;
  }

  if (blockIdx.x > 0) {
    // ---------------- prep blocks A/B/C (proven) ----------------
    const int g = (int)(blockIdx.x - 1) * 256 + tid;   // 0..7679
    const int c8 = g & 7;
    if (g < NSRC * 8) {
      int m = g >> 3;
      float myE = enh[128 + m], myI = inh[128 + m];
      int re = 0, ri = 0;
      for (int i = 112 * c8; i < 112 * c8 + 112; ++i) {
        float ev = enh[128 + i], iv = inh[128 + i];
        re += (ev < myE || (ev == myE && i < m)) ? 1 : 0;
        ri += (iv < myI || (iv == myI && i < m)) ? 1 : 0;
      }
      int p = re | (ri << 16);
      p += __shfl_xor(p, 1); p += __shfl_xor(p, 2); p += __shfl_xor(p, 4);
      if (c8 == 0) ast(&RK[m], ((u64)TAG_RK << 32) | (u32)p);
    }
    {
      int j = g >> 3;
      float cj = ident[64 + j];
      int ce = 0, ci = 0;
      for (int i = 112 * c8; i < 112 * c8 + 112; ++i) {
        ce += (enh[128 + i] <= cj) ? 1 : 0;
        ci += (inh[128 + i] <= cj) ? 1 : 0;
      }
      int p = ce | (ci << 16);
      p += __shfl_xor(p, 1); p += __shfl_xor(p, 2); p += __shfl_xor(p, 4);
      if (c8 == 0) ast(&CT[j], ((u64)TAG_CT << 32) | (u32)p);
    }
    {
      int j = g >> 3;
      float cj = ident[64 + j];
      float h = 0.0f;
      for (int k = 8 * c8; k < 8 * c8 + 8; ++k)
        h += expf(-bb * fabsf(enh[k] - cj)) - expf(-bb * fabsf(inh[k] - cj));
      h += __shfl_xor(h, 1); h += __shfl_xor(h, 2); h += __shfl_xor(h, 4);
      if (c8 == 0)
        ast(&HD[j], ((u64)TAG_HD << 32) |
                    (u64)__float_as_uint(dN * h * (1.0f / 1024.0f)));
    }
    return;
  }

  // ================= block 0: 1-wave scan (R9-proven, ported) =============
  if (tid >= 64) return;                 // no barriers in this path
  const int lane = tid;

  // stage tail-source transforms (own wave: 14 sources/lane)
  for (int m = lane; m < NSRC; m += 64) {
    float e = enh[128 + m], iv = inh[128 + m];
    SRCX[m] = make_float4(expf(bb * e), expf(-bb * e),
                          expf(bb * iv), expf(-bb * iv));
  }
  // zero all 1024 scan positions once (scatter rewrites 1..896 each iter;
  // 0 and 897..1023 stay zero: writeback below skips p > 896)
  #pragma unroll
  for (int u = 0; u < 16; ++u) {
    SE[u][lane] = make_float2(0.f, 0.f);
    SI[u][lane] = make_float2(0.f, 0.f);
  }
  asm volatile("s_waitcnt lgkmcnt(0)" ::: "memory");
  __builtin_amdgcn_sched_barrier(0);

  const int c0l = lane * 15;             // owns cols c0l..c0l+14 (960 = 64*15)
  float fmv[15], fpv[15], hdv[15], y[15];
  int cc[15], rr[15];
  #pragma unroll
  for (int s = 0; s < 15; ++s) {
    float cj = ident[64 + c0l + s];
    fmv[s] = expf(-bb * cj); fpv[s] = expf(bb * cj);
    y[s] = 1.0f / 1024.0f;
    rr[s] = 0;
  }
  #pragma unroll
  for (int s = 0; s < 15; ++s) {
    cc[s] = (int)poll32(&CT[c0l + s], TAG_CT);
    hdv[s] = __uint_as_float(poll32(&HD[c0l + s], TAG_HD));
  }
  #pragma unroll
  for (int s = 0; s < 15; ++s) {
    int c = c0l + s;
    if (c >= 64) rr[s] = (int)poll32(&RK[c - 64], TAG_RK);
  }

  for (int t = 0; t <= NWARM; ++t) {
    // scatter own sources by rank (source m = c-64 shares index s with col c)
    #pragma unroll
    for (int s = 0; s < 15; ++s) {
      int c = c0l + s;
      if (c >= 64) {
        float4 X = SRCX[c - 64];
        int qE = (rr[s] & 0xFFFF) + 1;
        int qI = ((rr[s] >> 16) & 0xFFFF) + 1;
        SE[qE & 15][qE >> 4] = make_float2(y[s] * X.x, y[s] * X.y);
        SI[qI & 15][qI >> 4] = make_float2(y[s] * X.z, y[s] * X.w);
      }
    }
    asm volatile("s_waitcnt lgkmcnt(0)" ::: "memory");
    __builtin_amdgcn_sched_barrier(0);

    // pass 1: lane totals over own 16 positions
    float2 tE = make_float2(0.f, 0.f), tI = make_float2(0.f, 0.f);
    #pragma unroll
    for (int u = 0; u < 16; ++u) {
      float2 a = SE[u][lane], b = SI[u][lane];
      tE.x += a.x; tE.y += a.y; tI.x += b.x; tI.y += b.y;
    }
    float4 inc = make_float4(tE.x, tE.y, tI.x, tI.y);
    float4 tot = inc;
    #pragma unroll
    for (int off = 1; off < 64; off <<= 1) {
      float ox = __shfl_up(inc.x, off, 64);
      float oy = __shfl_up(inc.y, off, 64);
      float oz = __shfl_up(inc.z, off, 64);
      float ow = __shfl_up(inc.w, off, 64);
      if (lane >= off) { inc.x += ox; inc.y += oy; inc.z += oz; inc.w += ow; }
    }
    float TEy = __shfl(inc.y, 63, 64);    // totals (zeros past 896)
    float TIy = __shfl(inc.w, 63, 64);
    float2 pe = make_float2(inc.x - tot.x, inc.y - tot.y);   // exclusive base
    float2 pi = make_float2(inc.z - tot.z, inc.w - tot.w);

    // pass 2: re-read + write back inclusive prefix (positions <= 896 only)
    #pragma unroll
    for (int u = 0; u < 16; ++u) {
      float2 a = SE[u][lane], b = SI[u][lane];
      pe.x += a.x; pe.y += a.y; pi.x += b.x; pi.y += b.y;
      if (lane * 16 + u <= NSRC) { SE[u][lane] = pe; SI[u][lane] = pi; }
    }
    asm volatile("s_waitcnt lgkmcnt(0)" ::: "memory");
    __builtin_amdgcn_sched_barrier(0);

    // combine at precomputed counts
    float nv[15]; float psum = 0.0f;
    #pragma unroll
    for (int s = 0; s < 15; ++s) {
      int cE = cc[s] & 0xFFFF, cI = (cc[s] >> 16) & 0xFFFF;
      float2 AE = SE[cE & 15][cE >> 4];
      float2 AI = SI[cI & 15][cI >> 4];
      float dot = fmv[s] * AE.x + fpv[s] * (TEy - AE.y)
                - fmv[s] * AI.x - fpv[s] * (TIy - AI.y);
      float pre = y[s] + dN * dot;
      if (t < NWARM) {
        nv[s] = fmaxf(pre + hdv[s], 0.0f);
        psum += nv[s];
      } else {
        base[c0l + s] = pre;              // plain store; K2 after boundary
      }
    }
    if (t < NWARM) {
      #pragma unroll
      for (int off = 32; off >= 1; off >>= 1) psum += __shfl_xor(psum, off);
      float invs = (psum > 0.0f) ? 1.0f / psum : 1.0f;
      #pragma unroll
      for (int s = 0; s < 15; ++s) y[s] = nv[s] * invs;
    }
  }
}

// K2: verbatim round-8 batch_k (passing, ~45 us by residual arithmetic).
// 512 blocks x 512 threads, 32 rows/block -> all 256 CUs at 2 blocks/CU.
// Weights streamed from the precomputed Wk table (L2-resident, built free
// under the scan); lane-contiguous conflict-free Wl reads; At padded for
// aligned b128; output chunk (cols 0..511) processed last -> live acc.
__global__ __launch_bounds__(512) void batch_k(const float* __restrict__ inp,
                                               const float* __restrict__ ws,
                                               float* __restrict__ out) {
  __shared__ float At[64][36];
  __shared__ float Wl[16][512];
  __shared__ float bch[NJ];

  const int tid = threadIdx.x;
  const int colg = tid & 63;
  const int rowg = tid >> 6;                 // 8 waves, 4 rows each
  const size_t rowbase = (size_t)blockIdx.x * 32;
  const float* __restrict__ Wk = ws + WK_F;

  {
    int r = tid >> 4, c4 = (tid & 15) * 4;   // 32 rows x 16 quads
    float4 f4 = *(const float4*)(inp + (rowbase + r) * 64 + c4);
    At[c4 + 0][r] = f4.x; At[c4 + 1][r] = f4.y;
    At[c4 + 2][r] = f4.z; At[c4 + 3][r] = f4.w;
  }
  if (tid < 240) {
    float4 b4 = *(const float4*)(ws + BASE_F + 4 * tid);
    bch[4 * tid + 0] = b4.x; bch[4 * tid + 1] = b4.y;
    bch[4 * tid + 2] = b4.z; bch[4 * tid + 3] = b4.w;
  }

  float acc[4][8];
  float rs[4] = {0.f, 0.f, 0.f, 0.f};

  #pragma unroll 1
  for (int ch = 0; ch < 2; ++ch) {
    const int c0 = ch ? 0 : 512;             // output chunk (cols 0..511) last

    #pragma unroll
    for (int r = 0; r < 4; ++r)
      #pragma unroll
      for (int c = 0; c < 8; ++c) acc[r][c] = 0.0f;

    #pragma unroll 1
    for (int s = 0; s < 4; ++s) {
      __syncthreads();
      #pragma unroll
      for (int i = 0; i < 4; ++i) {          // stage 16x512 Wl from Wk (L2)
        int fi = tid + i * 512;              // 0..2047
        int kk = fi >> 7;                    // 0..15
        int c4 = (fi & 127) * 4;             // 0..508
        int j = c0 + c4;
        float4 v = make_float4(0.f, 0.f, 0.f, 0.f);
        if (j < NJ)                          // j mult of 4 -> j<=956 full quad
          v = *(const float4*)(Wk + (size_t)(16 * s + kk) * NJ + j);
        *(float4*)&Wl[kk][c4] = v;
      }
      __syncthreads();
      #pragma unroll
      for (int kk = 0; kk < 16; ++kk) {
        float4 av = *(const float4*)&At[16 * s + kk][rowg * 4];  // bcast
        float4 w0 = *(const float4*)&Wl[kk][colg * 4];        // conflict-free
        float4 w1 = *(const float4*)&Wl[kk][256 + colg * 4];  // conflict-free
        float a_[4] = {av.x, av.y, av.z, av.w};
        float w_[8] = {w0.x, w0.y, w0.z, w0.w, w1.x, w1.y, w1.z, w1.w};
        #pragma unroll
        for (int r = 0; r < 4; ++r)
          #pragma unroll
          for (int c = 0; c < 8; ++c)
            acc[r][c] = fmaf(a_[r], w_[c], acc[r][c]);
      }
    }

    // per-chunk epilogue: relu row-sum (bias known from the start)
    #pragma unroll
    for (int c = 0; c < 8; ++c) {
      int cl = (c < 4) ? (colg * 4 + c) : (256 + colg * 4 + (c - 4));
      int j = c0 + cl;
      float bv = (j < NJ) ? bch[j] : -1.0e30f;   // acc is 0 there
      #pragma unroll
      for (int r = 0; r < 4; ++r)
        rs[r] += fmaxf(acc[r][c] + bv, 0.0f);
    }
  }

  #pragma unroll
  for (int r = 0; r < 4; ++r) {
    float v = rs[r];
    #pragma unroll
    for (int off = 32; off >= 1; off >>= 1) v += __shfl_xor(v, off);
    rs[r] = v;
  }
  if (colg < 16) {
    #pragma unroll
    for (int r = 0; r < 4; ++r) {
      float inv = (rs[r] > 0.0f) ? 1.0f / rs[r] : 1.0f;
      float* op = out + (rowbase + rowg * 4 + r) * 64 + colg * 4;
      float4 o;
      o.x = fmaxf(acc[r][0] + bch[colg * 4 + 0], 0.0f) * inv;
      o.y = fmaxf(acc[r][1] + bch[colg * 4 + 1], 0.0f) * inv;
      o.z = fmaxf(acc[r][2] + bch[colg * 4 + 2], 0.0f) * inv;
      o.w = fmaxf(acc[r][3] + bch[colg * 4 + 3], 0.0f) * inv;
      *(float4*)op = o;
    }
  }
}

extern "C" void kernel_launch(void* const* d_in, const int* in_sizes, int n_in,
                              void* d_out, int out_size, void* d_ws, size_t ws_size,
                              hipStream_t stream) {
  const float* inp   = (const float*)d_in[0];
  const float* ident = (const float*)d_in[1];
  const float* enh   = (const float*)d_in[2];
  const float* inh   = (const float*)d_in[3];
  const float* beta  = (const float*)d_in[4];
  const float* delta = (const float*)d_in[5];

  hipLaunchKernelGGL(front_k, dim3(61), dim3(256), 0, stream,
                     ident, enh, inh, beta, delta, d_ws);
  hipLaunchKernelGGL(batch_k, dim3(512), dim3(512), 0, stream,
                     inp, (const float*)d_ws, (float*)d_out);
}

// Round 11
// 173.842 us; speedup vs baseline: 1.1940x; 1.0662x over previous
//
#include <hip/hip_runtime.h>
#include <math.h>

#define NJ 960           // tail columns (global 64..1023)
#define NSRC 896         // tail sources (global 128..1023)
#define NWARM 25

typedef unsigned long long u64;
typedef unsigned int u32;

// ws layout:
//   u64 idx: RK[896] tag|(rE|rI<<16), CT[960] tag|(cntE|cntI<<16),
//            HD[960] tag|float(hd[j])
//   float idx 8192 : Wk[64][960]  (built by front_k blocks 16..30)
//   float idx 69632: base[960]    (plain floats; K1->K2 kernel boundary orders)
#define RK_O 0u
#define CT_O 896u
#define HD_O 1856u
#define WK_F 8192u
#define BASE_F 69632u

#define TAG_RK 0x524B0001u
#define TAG_CT 0x43540001u
#define TAG_HD 0x48440001u

__device__ __forceinline__ void ast(u64* p, u64 v) {
  __hip_atomic_store(p, v, __ATOMIC_RELAXED, __HIP_MEMORY_SCOPE_AGENT);
}
__device__ __forceinline__ u64 ald(const u64* p) {
  return __hip_atomic_load(p, __ATOMIC_RELAXED, __HIP_MEMORY_SCOPE_AGENT);
}
__device__ __forceinline__ u32 poll32(const u64* p, u32 tag) {
  u64 v = ald(p);
  while ((u32)(v >> 32) != tag) { __builtin_amdgcn_s_sleep(8); v = ald(p); }
  return (u32)v;
}

// K1, grid 31 x 512:
//   block 0     : warmup scan on 8 WAVES, 2 positions/thread. R10 falsified
//                 the 1-wave design (96us: no TLP to hide LDS latency); this
//                 goes the other way from the proven 4-wave/2.4us-iter
//                 version: halve per-phase chains, keep the same skeleton.
//                 4 barriers/iter (normalization folded into scatter via
//                 unnormalized yl + ssw-derived inv; zero-fill hoisted).
//   blocks 1..15 : prep A/B/C (ranks/counts/hd), tag-published (proven)
//   blocks 16..30: part D (Wk table), separate blocks (proven: keeps heavy
//                  exp loops off the scan's CU)
__global__ __launch_bounds__(512, 1) void front_k(
    const float* __restrict__ ident, const float* __restrict__ enh,
    const float* __restrict__ inh, const float* __restrict__ beta,
    const float* __restrict__ delta, void* __restrict__ wsv) {
  __shared__ float2 scanE[1024];
  __shared__ float2 scanI[1024];
  __shared__ float yl[NJ];        // UNNORMALIZED nv; readers apply inv
  __shared__ float ssw[8];        // per-wave psum partials
  __shared__ float4 wtot[8];

  u64* RK = (u64*)wsv + RK_O;
  u64* CT = (u64*)wsv + CT_O;
  u64* HD = (u64*)wsv + HD_O;
  float* Wk = (float*)wsv + WK_F;
  float* base = (float*)wsv + BASE_F;

  const int tid = threadIdx.x;
  const float bb = beta[0];
  const float dN = delta[0] / 1024.0f;

  if (blockIdx.x >= 16) {
    // ---------------- part D: Wk table (proven; 512-thread mapping) -------
    const int g2 = (int)(blockIdx.x - 16) * 512 + tid;   // 0..7679
    int k = g2 / 120;
    int jb = (g2 % 120) * 8;
    float ek = enh[k], ik = inh[k];
    #pragma unroll
    for (int u = 0; u < 8; ++u) {
      float cj = ident[64 + jb + u];
      Wk[(size_t)k * NJ + jb + u] =
          dN * (expf(-bb * fabsf(ek - cj)) - expf(-bb * fabsf(ik - cj)));
    }
    return;
  }

  if (blockIdx.x >= 1) {
    // ---------------- prep blocks A/B/C (proven; 512-thread mapping) ------
    const int g = (int)(blockIdx.x - 1) * 512 + tid;   // 0..7679
    const int c8 = g & 7;
    if (g < NSRC * 8) {
      int m = g >> 3;
      float myE = enh[128 + m], myI = inh[128 + m];
      int re = 0, ri = 0;
      for (int i = 112 * c8; i < 112 * c8 + 112; ++i) {
        float ev = enh[128 + i], iv = inh[128 + i];
        re += (ev < myE || (ev == myE && i < m)) ? 1 : 0;
        ri += (iv < myI || (iv == myI && i < m)) ? 1 : 0;
      }
      int p = re | (ri << 16);
      p += __shfl_xor(p, 1); p += __shfl_xor(p, 2); p += __shfl_xor(p, 4);
      if (c8 == 0) ast(&RK[m], ((u64)TAG_RK << 32) | (u32)p);
    }
    {
      int j = g >> 3;
      float cj = ident[64 + j];
      int ce = 0, ci = 0;
      for (int i = 112 * c8; i < 112 * c8 + 112; ++i) {
        ce += (enh[128 + i] <= cj) ? 1 : 0;
        ci += (inh[128 + i] <= cj) ? 1 : 0;
      }
      int p = ce | (ci << 16);
      p += __shfl_xor(p, 1); p += __shfl_xor(p, 2); p += __shfl_xor(p, 4);
      if (c8 == 0) ast(&CT[j], ((u64)TAG_CT << 32) | (u32)p);
    }
    {
      int j = g >> 3;
      float cj = ident[64 + j];
      float h = 0.0f;
      for (int k = 8 * c8; k < 8 * c8 + 8; ++k)
        h += expf(-bb * fabsf(enh[k] - cj)) - expf(-bb * fabsf(inh[k] - cj));
      h += __shfl_xor(h, 1); h += __shfl_xor(h, 2); h += __shfl_xor(h, 4);
      if (c8 == 0)
        ast(&HD[j], ((u64)TAG_HD << 32) |
                    (u64)__float_as_uint(dN * h * (1.0f / 1024.0f)));
    }
    return;
  }

  // ================= block 0: 8-wave scan, 2 positions/thread =============
  const int lane = tid & 63, wvid = tid >> 6;
  const int p0 = 2 * tid;               // owned scan positions p0, p0+1
  const int j0 = 2 * tid;               // owned columns j0, j0+1 (tid<480)
  const bool hasCol = tid < 480;
  const bool hasSrc = tid < 448;        // owned sources m = j0, j0+1

  // one-time zeros: scatter rewrites 1..896 each iter; 0 and 897..1023 stay 0
  scanE[p0] = make_float2(0.f, 0.f); scanE[p0 + 1] = make_float2(0.f, 0.f);
  scanI[p0] = make_float2(0.f, 0.f); scanI[p0 + 1] = make_float2(0.f, 0.f);
  if (hasCol) { yl[j0] = 1.0f / 1024.0f; yl[j0 + 1] = 1.0f / 1024.0f; }
  if (tid < 8) ssw[tid] = 0.125f;       // sum 1 -> inv=1 at t=0

  // per-column constants
  float fmv[2], fpv[2], hdv[2];
  int cc[2] = {0, 0};
  if (hasCol) {
    #pragma unroll
    for (int s = 0; s < 2; ++s) {
      float cj = ident[64 + j0 + s];
      fmv[s] = expf(-bb * cj); fpv[s] = expf(bb * cj);
      cc[s] = (int)poll32(&CT[j0 + s], TAG_CT);
      hdv[s] = __uint_as_float(poll32(&HD[j0 + s], TAG_HD));
    }
  }
  // per-source constants
  float4 X[2];
  int rr[2] = {0, 0};
  if (hasSrc) {
    #pragma unroll
    for (int s = 0; s < 2; ++s) {
      int m = j0 + s;
      float e = enh[128 + m], iv = inh[128 + m];
      X[s] = make_float4(expf(bb * e), expf(-bb * e),
                         expf(bb * iv), expf(-bb * iv));
      rr[s] = (int)poll32(&RK[m], TAG_RK);
    }
  }
  float nv[2] = {1.0f / 1024.0f, 1.0f / 1024.0f};
  __syncthreads();

  for (int t = 0; t <= NWARM; ++t) {
    // inv from previous iteration's partials (deterministic, same division)
    float ssum = ssw[0] + ssw[1] + ssw[2] + ssw[3]
               + ssw[4] + ssw[5] + ssw[6] + ssw[7];
    float inv = (ssum > 0.0f) ? 1.0f / ssum : 1.0f;

    // scatter own sources by rank (value = normalized y * transform)
    if (hasSrc) {
      #pragma unroll
      for (int s = 0; s < 2; ++s) {
        float ym = yl[64 + j0 + s] * inv;
        scanE[(rr[s] & 0xFFFF) + 1] = make_float2(ym * X[s].x, ym * X[s].y);
        scanI[((rr[s] >> 16) & 0xFFFF) + 1] =
            make_float2(ym * X[s].z, ym * X[s].w);
      }
    }
    __syncthreads();   // A: scatter visible (also: prior-iter gathers done)

    // prefix: local(2) + wave scan + cross-wave
    float2 e0 = scanE[p0], e1v = scanE[p0 + 1];
    float2 i0 = scanI[p0], i1v = scanI[p0 + 1];
    float4 tot = make_float4(e0.x + e1v.x, e0.y + e1v.y,
                             i0.x + i1v.x, i0.y + i1v.y);
    float4 inc = tot;
    #pragma unroll
    for (int off = 1; off < 64; off <<= 1) {
      float ox = __shfl_up(inc.x, off, 64);
      float oy = __shfl_up(inc.y, off, 64);
      float oz = __shfl_up(inc.z, off, 64);
      float ow = __shfl_up(inc.w, off, 64);
      if (lane >= off) { inc.x += ox; inc.y += oy; inc.z += oz; inc.w += ow; }
    }
    if (lane == 63) wtot[wvid] = inc;
    __syncthreads();   // B: wave totals visible

    float4 exc = make_float4(inc.x - tot.x, inc.y - tot.y,
                             inc.z - tot.z, inc.w - tot.w);
    float4 tsum = make_float4(0.f, 0.f, 0.f, 0.f);
    #pragma unroll
    for (int w = 0; w < 8; ++w) {
      float4 p = wtot[w];
      if (w < wvid) { exc.x += p.x; exc.y += p.y; exc.z += p.z; exc.w += p.w; }
      tsum.x += p.x; tsum.y += p.y; tsum.z += p.z; tsum.w += p.w;
    }
    float2 pe0 = make_float2(exc.x + e0.x, exc.y + e0.y);
    float2 pe1 = make_float2(pe0.x + e1v.x, pe0.y + e1v.y);
    float2 pi0 = make_float2(exc.z + i0.x, exc.w + i0.y);
    float2 pi1 = make_float2(pi0.x + i1v.x, pi0.y + i1v.y);
    if (p0 <= NSRC) { scanE[p0] = pe0; scanI[p0] = pi0; }
    if (p0 + 1 <= NSRC) { scanE[p0 + 1] = pe1; scanI[p0 + 1] = pi1; }
    __syncthreads();   // C: inclusive prefix visible

    // combine at precomputed counts
    float psum = 0.0f;
    if (hasCol) {
      #pragma unroll
      for (int s = 0; s < 2; ++s) {
        float y_own = nv[s] * inv;
        int cE = cc[s] & 0xFFFF, cI = (cc[s] >> 16) & 0xFFFF;
        float2 AE = scanE[cE], AI = scanI[cI];
        float dot = fmv[s] * AE.x + fpv[s] * (tsum.y - AE.y)
                  - fmv[s] * AI.x - fpv[s] * (tsum.w - AI.y);
        float pre = y_own + dN * dot;
        if (t < NWARM) {
          nv[s] = fmaxf(pre + hdv[s], 0.0f);
          psum += nv[s];
        } else {
          base[j0 + s] = pre;           // plain store; K2 after boundary
        }
      }
    }
    if (t < NWARM) {
      #pragma unroll
      for (int off = 32; off >= 1; off >>= 1) psum += __shfl_xor(psum, off);
      if (lane == 0) ssw[wvid] = psum;
      if (hasCol) { yl[j0] = nv[0]; yl[j0 + 1] = nv[1]; }
      __syncthreads(); // X: yl/ssw visible; scanE free for next scatter
    }
  }
}

// K2: verbatim round-8 batch_k (proven). 512 blocks x 512 threads,
// 32 rows/block -> all 256 CUs at 2 blocks/CU. Weights streamed from the
// precomputed Wk table; lane-contiguous conflict-free Wl reads; output
// chunk (cols 0..511) processed last -> stores from live acc.
__global__ __launch_bounds__(512) void batch_k(const float* __restrict__ inp,
                                               const float* __restrict__ ws,
                                               float* __restrict__ out) {
  __shared__ float At[64][36];
  __shared__ float Wl[16][512];
  __shared__ float bch[NJ];

  const int tid = threadIdx.x;
  const int colg = tid & 63;
  const int rowg = tid >> 6;                 // 8 waves, 4 rows each
  const size_t rowbase = (size_t)blockIdx.x * 32;
  const float* __restrict__ Wk = ws + WK_F;

  {
    int r = tid >> 4, c4 = (tid & 15) * 4;   // 32 rows x 16 quads
    float4 f4 = *(const float4*)(inp + (rowbase + r) * 64 + c4);
    At[c4 + 0][r] = f4.x; At[c4 + 1][r] = f4.y;
    At[c4 + 2][r] = f4.z; At[c4 + 3][r] = f4.w;
  }
  if (tid < 240) {
    float4 b4 = *(const float4*)(ws + BASE_F + 4 * tid);
    bch[4 * tid + 0] = b4.x; bch[4 * tid + 1] = b4.y;
    bch[4 * tid + 2] = b4.z; bch[4 * tid + 3] = b4.w;
  }

  float acc[4][8];
  float rs[4] = {0.f, 0.f, 0.f, 0.f};

  #pragma unroll 1
  for (int ch = 0; ch < 2; ++ch) {
    const int c0 = ch ? 0 : 512;             // output chunk (cols 0..511) last

    #pragma unroll
    for (int r = 0; r < 4; ++r)
      #pragma unroll
      for (int c = 0; c < 8; ++c) acc[r][c] = 0.0f;

    #pragma unroll 1
    for (int s = 0; s < 4; ++s) {
      __syncthreads();
      #pragma unroll
      for (int i = 0; i < 4; ++i) {          // stage 16x512 Wl from Wk (L2)
        int fi = tid + i * 512;              // 0..2047
        int kk = fi >> 7;                    // 0..15
        int c4 = (fi & 127) * 4;             // 0..508
        int j = c0 + c4;
        float4 v = make_float4(0.f, 0.f, 0.f, 0.f);
        if (j < NJ)                          // j mult of 4 -> j<=956 full quad
          v = *(const float4*)(Wk + (size_t)(16 * s + kk) * NJ + j);
        *(float4*)&Wl[kk][c4] = v;
      }
      __syncthreads();
      #pragma unroll
      for (int kk = 0; kk < 16; ++kk) {
        float4 av = *(const float4*)&At[16 * s + kk][rowg * 4];  // bcast
        float4 w0 = *(const float4*)&Wl[kk][colg * 4];        // conflict-free
        float4 w1 = *(const float4*)&Wl[kk][256 + colg * 4];  // conflict-free
        float a_[4] = {av.x, av.y, av.z, av.w};
        float w_[8] = {w0.x, w0.y, w0.z, w0.w, w1.x, w1.y, w1.z, w1.w};
        #pragma unroll
        for (int r = 0; r < 4; ++r)
          #pragma unroll
          for (int c = 0; c < 8; ++c)
            acc[r][c] = fmaf(a_[r], w_[c], acc[r][c]);
      }
    }

    // per-chunk epilogue: relu row-sum (bias known from the start)
    #pragma unroll
    for (int c = 0; c < 8; ++c) {
      int cl = (c < 4) ? (colg * 4 + c) : (256 + colg * 4 + (c - 4));
      int j = c0 + cl;
      float bv = (j < NJ) ? bch[j] : -1.0e30f;   // acc is 0 there
      #pragma unroll
      for (int r = 0; r < 4; ++r)
        rs[r] += fmaxf(acc[r][c] + bv, 0.0f);
    }
  }

  #pragma unroll
  for (int r = 0; r < 4; ++r) {
    float v = rs[r];
    #pragma unroll
    for (int off = 32; off >= 1; off >>= 1) v += __shfl_xor(v, off);
    rs[r] = v;
  }
  if (colg < 16) {
    #pragma unroll
    for (int r = 0; r < 4; ++r) {
      float inv = (rs[r] > 0.0f) ? 1.0f / rs[r] : 1.0f;
      float* op = out + (rowbase + rowg * 4 + r) * 64 + colg * 4;
      float4 o;
      o.x = fmaxf(acc[r][0] + bch[colg * 4 + 0], 0.0f) * inv;
      o.y = fmaxf(acc[r][1] + bch[colg * 4 + 1], 0.0f) * inv;
      o.z = fmaxf(acc[r][2] + bch[colg * 4 + 2], 0.0f) * inv;
      o.w = fmaxf(acc[r][3] + bch[colg * 4 + 3], 0.0f) * inv;
      *(float4*)op = o;
    }
  }
}

extern "C" void kernel_launch(void* const* d_in, const int* in_sizes, int n_in,
                              void* d_out, int out_size, void* d_ws, size_t ws_size,
                              hipStream_t stream) {
  const float* inp   = (const float*)d_in[0];
  const float* ident = (const float*)d_in[1];
  const float* enh   = (const float*)d_in[2];
  const float* inh   = (const float*)d_in[3];
  const float* beta  = (const float*)d_in[4];
  const float* delta = (const float*)d_in[5];

  hipLaunchKernelGGL(front_k, dim3(31), dim3(512), 0, stream,
                     ident, enh, inh, beta, delta, d_ws);
  hipLaunchKernelGGL(batch_k, dim3(512), dim3(512), 0, stream,
                     inp, (const float*)d_ws, (float*)d_out);
}

// Round 12
// 157.158 us; speedup vs baseline: 1.3208x; 1.1062x over previous
//
#include <hip/hip_runtime.h>
#include <math.h>

#define NJ 960           // tail columns (global 64..1023)
#define NSRC 896         // tail sources (global 128..1023)
#define NWARM 25

typedef unsigned long long u64;
typedef unsigned int u32;

// ws layout:
//   u64 idx: RK[896] tag|(rE|rI<<16), CT[960] tag|(cntE|cntI<<16),
//            HD[960] tag|float(hd[j])
//   float idx 8192 : Wk[64][960]  (built by front_k blocks 31..60)
//   float idx 69632: base[960]    (plain floats; K1->K2 kernel boundary orders)
#define RK_O 0u
#define CT_O 896u
#define HD_O 1856u
#define WK_F 8192u
#define BASE_F 69632u

#define TAG_RK 0x524B0001u
#define TAG_CT 0x43540001u
#define TAG_HD 0x48440001u

__device__ __forceinline__ void ast(u64* p, u64 v) {
  __hip_atomic_store(p, v, __ATOMIC_RELAXED, __HIP_MEMORY_SCOPE_AGENT);
}
__device__ __forceinline__ u64 ald(const u64* p) {
  return __hip_atomic_load(p, __ATOMIC_RELAXED, __HIP_MEMORY_SCOPE_AGENT);
}
__device__ __forceinline__ u32 poll32(const u64* p, u32 tag) {
  u64 v = ald(p);
  while ((u32)(v >> 32) != tag) { __builtin_amdgcn_s_sleep(8); v = ald(p); }
  return (u32)v;
}

// K1, grid 61 x 256 (R8 layout):
//   block 0      : 4-WAVE scan (measured optimum: 1w=3.7, 4w=2.4, 8w=3.6
//                  us/iter) now on R11's proven 4-barrier skeleton:
//                  normalization folded into scatter (unnormalized yl +
//                  ssw-derived inv — bit-compatible per R11), zero-fill
//                  hoisted (writeback guarded to p<=896).
//   blocks 1..30 : prep A/B/C (ranks/counts/hd), tag-published (proven)
//   blocks 31..60: part D (Wk table), separate blocks (proven: keeps heavy
//                  exp loops off the scan's CU)
__global__ __launch_bounds__(256) void front_k(const float* __restrict__ ident,
                                               const float* __restrict__ enh,
                                               const float* __restrict__ inh,
                                               const float* __restrict__ beta,
                                               const float* __restrict__ delta,
                                               void* __restrict__ wsv) {
  __shared__ float2 scanE[1024];
  __shared__ float2 scanI[1024];
  __shared__ float yl[NJ];        // UNNORMALIZED nv; readers apply inv
  __shared__ float ssw[4];        // per-wave psum partials
  __shared__ float4 wtot[4];

  u64* RK = (u64*)wsv + RK_O;
  u64* CT = (u64*)wsv + CT_O;
  u64* HD = (u64*)wsv + HD_O;
  float* Wk = (float*)wsv + WK_F;
  float* base = (float*)wsv + BASE_F;

  const int tid = threadIdx.x;
  const float bb = beta[0];
  const float dN = delta[0] / 1024.0f;

  if (blockIdx.x > 30) {
    // ---------------- part D: Wk table (proven) ----------------
    const int g2 = (int)(blockIdx.x - 31) * 256 + tid;   // 0..7679
    int k = g2 / 120;
    int jb = (g2 % 120) * 8;
    float ek = enh[k], ik = inh[k];
    #pragma unroll
    for (int u = 0; u < 8; ++u) {
      float cj = ident[64 + jb + u];
      Wk[(size_t)k * NJ + jb + u] =
          dN * (expf(-bb * fabsf(ek - cj)) - expf(-bb * fabsf(ik - cj)));
    }
    return;
  }

  if (blockIdx.x > 0) {
    // ---------------- prep blocks A/B/C (proven) ----------------
    const int g = (int)(blockIdx.x - 1) * 256 + tid;   // 0..7679
    const int c8 = g & 7;
    if (g < NSRC * 8) {
      int m = g >> 3;
      float myE = enh[128 + m], myI = inh[128 + m];
      int re = 0, ri = 0;
      for (int i = 112 * c8; i < 112 * c8 + 112; ++i) {
        float ev = enh[128 + i], iv = inh[128 + i];
        re += (ev < myE || (ev == myE && i < m)) ? 1 : 0;
        ri += (iv < myI || (iv == myI && i < m)) ? 1 : 0;
      }
      int p = re | (ri << 16);
      p += __shfl_xor(p, 1); p += __shfl_xor(p, 2); p += __shfl_xor(p, 4);
      if (c8 == 0) ast(&RK[m], ((u64)TAG_RK << 32) | (u32)p);
    }
    {
      int j = g >> 3;
      float cj = ident[64 + j];
      int ce = 0, ci = 0;
      for (int i = 112 * c8; i < 112 * c8 + 112; ++i) {
        ce += (enh[128 + i] <= cj) ? 1 : 0;
        ci += (inh[128 + i] <= cj) ? 1 : 0;
      }
      int p = ce | (ci << 16);
      p += __shfl_xor(p, 1); p += __shfl_xor(p, 2); p += __shfl_xor(p, 4);
      if (c8 == 0) ast(&CT[j], ((u64)TAG_CT << 32) | (u32)p);
    }
    {
      int j = g >> 3;
      float cj = ident[64 + j];
      float h = 0.0f;
      for (int k = 8 * c8; k < 8 * c8 + 8; ++k)
        h += expf(-bb * fabsf(enh[k] - cj)) - expf(-bb * fabsf(inh[k] - cj));
      h += __shfl_xor(h, 1); h += __shfl_xor(h, 2); h += __shfl_xor(h, 4);
      if (c8 == 0)
        ast(&HD[j], ((u64)TAG_HD << 32) |
                    (u64)__float_as_uint(dN * h * (1.0f / 1024.0f)));
    }
    return;
  }

  // ========== block 0: 4-wave scan, 4-barrier iteration ==========
  const int lane = tid & 63, wvid = tid >> 6;

  // one-time zero-fill: scatter rewrites 1..896 each iter; writeback is
  // guarded to p<=896, so 0 and 897..1023 stay zero forever.
  #pragma unroll
  for (int s = 0; s < 4; ++s) {
    scanE[4 * tid + s] = make_float2(0.f, 0.f);
    scanI[4 * tid + s] = make_float2(0.f, 0.f);
  }
  if (tid < 4) ssw[tid] = 0.25f;        // sum 1 -> inv = 1 at t = 0
  if (tid < 240) {
    #pragma unroll
    for (int c = 0; c < 4; ++c) yl[4 * tid + c] = 1.0f / 1024.0f;
  }

  int rE[4], rI[4];
  if (tid < 224) {
    #pragma unroll
    for (int s = 0; s < 4; ++s) {
      u32 v = poll32(&RK[4 * tid + s], TAG_RK);
      rE[s] = v & 0xFFFF; rI[s] = v >> 16;
    }
  }
  int cE[4], cI[4];
  float hd[4], fm[4], fp[4];
  if (tid < 240) {
    #pragma unroll
    for (int c = 0; c < 4; ++c) {
      u32 v = poll32(&CT[4 * tid + c], TAG_CT);
      cE[c] = v & 0xFFFF; cI[c] = v >> 16;
      hd[c] = __uint_as_float(poll32(&HD[4 * tid + c], TAG_HD));
      float cj = ident[64 + 4 * tid + c];
      fm[c] = expf(-bb * cj); fp[c] = expf(bb * cj);
    }
  }
  float EP[4], EN[4], IP[4], IN2[4];
  if (tid < 224) {
    #pragma unroll
    for (int s = 0; s < 4; ++s) {
      float e = enh[128 + 4 * tid + s], i2 = inh[128 + 4 * tid + s];
      EP[s] = expf(bb * e);  EN[s] = expf(-bb * e);
      IP[s] = expf(bb * i2); IN2[s] = expf(-bb * i2);
    }
  }
  float nv[4] = {1.0f / 1024.0f, 1.0f / 1024.0f, 1.0f / 1024.0f, 1.0f / 1024.0f};
  __syncthreads();

  for (int t = 0; t <= NWARM; ++t) {
    // inv from previous iteration's partials (deterministic, same division)
    float ssum = ssw[0] + ssw[1] + ssw[2] + ssw[3];
    float inv = (ssum > 0.0f) ? 1.0f / ssum : 1.0f;

    // scatter own sources by rank (value = normalized y * transform)
    if (tid < 224) {
      #pragma unroll
      for (int s = 0; s < 4; ++s) {
        float ym = yl[64 + 4 * tid + s] * inv;
        scanE[rE[s] + 1] = make_float2(ym * EP[s], ym * EN[s]);
        scanI[rI[s] + 1] = make_float2(ym * IP[s], ym * IN2[s]);
      }
    }
    __syncthreads();   // A: scatter visible (prior-iter gathers also done)

    // local prefix (4 positions) + wave scan of totals
    float2 e0 = scanE[4 * tid], e1 = scanE[4 * tid + 1],
           e2 = scanE[4 * tid + 2], e3 = scanE[4 * tid + 3];
    float2 i0 = scanI[4 * tid], i1 = scanI[4 * tid + 1],
           i2v = scanI[4 * tid + 2], i3 = scanI[4 * tid + 3];
    e1.x += e0.x; e1.y += e0.y; e2.x += e1.x; e2.y += e1.y; e3.x += e2.x; e3.y += e2.y;
    i1.x += i0.x; i1.y += i0.y; i2v.x += i1.x; i2v.y += i1.y; i3.x += i2v.x; i3.y += i2v.y;
    float4 tot = make_float4(e3.x, e3.y, i3.x, i3.y);
    float4 inc = tot;
    #pragma unroll
    for (int off = 1; off < 64; off <<= 1) {
      float ox = __shfl_up(inc.x, off, 64);
      float oy = __shfl_up(inc.y, off, 64);
      float oz = __shfl_up(inc.z, off, 64);
      float ow = __shfl_up(inc.w, off, 64);
      if (lane >= off) { inc.x += ox; inc.y += oy; inc.z += oz; inc.w += ow; }
    }
    if (lane == 63) wtot[wvid] = inc;
    __syncthreads();   // B: wave totals visible

    float4 exc = make_float4(inc.x - tot.x, inc.y - tot.y,
                             inc.z - tot.z, inc.w - tot.w);
    float4 tsum = make_float4(0.f, 0.f, 0.f, 0.f);
    #pragma unroll
    for (int w = 0; w < 4; ++w) {
      float4 p = wtot[w];
      if (w < wvid) { exc.x += p.x; exc.y += p.y; exc.z += p.z; exc.w += p.w; }
      tsum.x += p.x; tsum.y += p.y; tsum.z += p.z; tsum.w += p.w;
    }
    e0.x += exc.x; e0.y += exc.y; e1.x += exc.x; e1.y += exc.y;
    e2.x += exc.x; e2.y += exc.y; e3.x += exc.x; e3.y += exc.y;
    i0.x += exc.z; i0.y += exc.w; i1.x += exc.z; i1.y += exc.w;
    i2v.x += exc.z; i2v.y += exc.w; i3.x += exc.z; i3.y += exc.w;
    // writeback guarded to p <= 896 (keeps hoisted zeros intact)
    {
      int p0 = 4 * tid;
      if (p0 <= NSRC)     { scanE[p0] = e0;     scanI[p0] = i0; }
      if (p0 + 1 <= NSRC) { scanE[p0 + 1] = e1; scanI[p0 + 1] = i1; }
      if (p0 + 2 <= NSRC) { scanE[p0 + 2] = e2; scanI[p0 + 2] = i2v; }
      if (p0 + 3 <= NSRC) { scanE[p0 + 3] = e3; scanI[p0 + 3] = i3; }
    }
    __syncthreads();   // C: inclusive prefix visible

    // combine at precomputed counts (totals from tsum: positions>896 are 0)
    float psum = 0.0f;
    if (tid < 240) {
      #pragma unroll
      for (int c = 0; c < 4; ++c) {
        float y_own = nv[c] * inv;
        float2 AE = scanE[cE[c]], AI = scanI[cI[c]];
        float dot = fm[c] * AE.x + fp[c] * (tsum.y - AE.y)
                  - fm[c] * AI.x - fp[c] * (tsum.w - AI.y);
        float pre = y_own + dN * dot;
        if (t < NWARM) {
          nv[c] = fmaxf(pre + hd[c], 0.0f);
          psum += nv[c];
        } else {
          base[4 * tid + c] = pre;      // plain store; K2 after boundary
        }
      }
    }
    if (t < NWARM) {
      #pragma unroll
      for (int off = 32; off >= 1; off >>= 1) psum += __shfl_xor(psum, off);
      if (lane == 0) ssw[wvid] = psum;
      if (tid < 240) {
        #pragma unroll
        for (int c = 0; c < 4; ++c) yl[4 * tid + c] = nv[c];
      }
      __syncthreads(); // X: yl/ssw visible; scan arrays free for next scatter
    }
  }
}

// K2: verbatim round-8 batch_k (proven). 512 blocks x 512 threads,
// 32 rows/block -> all 256 CUs at 2 blocks/CU. Weights streamed from the
// precomputed Wk table; lane-contiguous conflict-free Wl reads; output
// chunk (cols 0..511) processed last -> stores from live acc.
__global__ __launch_bounds__(512) void batch_k(const float* __restrict__ inp,
                                               const float* __restrict__ ws,
                                               float* __restrict__ out) {
  __shared__ float At[64][36];
  __shared__ float Wl[16][512];
  __shared__ float bch[NJ];

  const int tid = threadIdx.x;
  const int colg = tid & 63;
  const int rowg = tid >> 6;                 // 8 waves, 4 rows each
  const size_t rowbase = (size_t)blockIdx.x * 32;
  const float* __restrict__ Wk = ws + WK_F;

  {
    int r = tid >> 4, c4 = (tid & 15) * 4;   // 32 rows x 16 quads
    float4 f4 = *(const float4*)(inp + (rowbase + r) * 64 + c4);
    At[c4 + 0][r] = f4.x; At[c4 + 1][r] = f4.y;
    At[c4 + 2][r] = f4.z; At[c4 + 3][r] = f4.w;
  }
  if (tid < 240) {
    float4 b4 = *(const float4*)(ws + BASE_F + 4 * tid);
    bch[4 * tid + 0] = b4.x; bch[4 * tid + 1] = b4.y;
    bch[4 * tid + 2] = b4.z; bch[4 * tid + 3] = b4.w;
  }

  float acc[4][8];
  float rs[4] = {0.f, 0.f, 0.f, 0.f};

  #pragma unroll 1
  for (int ch = 0; ch < 2; ++ch) {
    const int c0 = ch ? 0 : 512;             // output chunk (cols 0..511) last

    #pragma unroll
    for (int r = 0; r < 4; ++r)
      #pragma unroll
      for (int c = 0; c < 8; ++c) acc[r][c] = 0.0f;

    #pragma unroll 1
    for (int s = 0; s < 4; ++s) {
      __syncthreads();
      #pragma unroll
      for (int i = 0; i < 4; ++i) {          // stage 16x512 Wl from Wk (L2)
        int fi = tid + i * 512;              // 0..2047
        int kk = fi >> 7;                    // 0..15
        int c4 = (fi & 127) * 4;             // 0..508
        int j = c0 + c4;
        float4 v = make_float4(0.f, 0.f, 0.f, 0.f);
        if (j < NJ)                          // j mult of 4 -> j<=956 full quad
          v = *(const float4*)(Wk + (size_t)(16 * s + kk) * NJ + j);
        *(float4*)&Wl[kk][c4] = v;
      }
      __syncthreads();
      #pragma unroll
      for (int kk = 0; kk < 16; ++kk) {
        float4 av = *(const float4*)&At[16 * s + kk][rowg * 4];  // bcast
        float4 w0 = *(const float4*)&Wl[kk][colg * 4];        // conflict-free
        float4 w1 = *(const float4*)&Wl[kk][256 + colg * 4];  // conflict-free
        float a_[4] = {av.x, av.y, av.z, av.w};
        float w_[8] = {w0.x, w0.y, w0.z, w0.w, w1.x, w1.y, w1.z, w1.w};
        #pragma unroll
        for (int r = 0; r < 4; ++r)
          #pragma unroll
          for (int c = 0; c < 8; ++c)
            acc[r][c] = fmaf(a_[r], w_[c], acc[r][c]);
      }
    }

    // per-chunk epilogue: relu row-sum (bias known from the start)
    #pragma unroll
    for (int c = 0; c < 8; ++c) {
      int cl = (c < 4) ? (colg * 4 + c) : (256 + colg * 4 + (c - 4));
      int j = c0 + cl;
      float bv = (j < NJ) ? bch[j] : -1.0e30f;   // acc is 0 there
      #pragma unroll
      for (int r = 0; r < 4; ++r)
        rs[r] += fmaxf(acc[r][c] + bv, 0.0f);
    }
  }

  #pragma unroll
  for (int r = 0; r < 4; ++r) {
    float v = rs[r];
    #pragma unroll
    for (int off = 32; off >= 1; off >>= 1) v += __shfl_xor(v, off);
    rs[r] = v;
  }
  if (colg < 16) {
    #pragma unroll
    for (int r = 0; r < 4; ++r) {
      float inv = (rs[r] > 0.0f) ? 1.0f / rs[r] : 1.0f;
      float* op = out + (rowbase + rowg * 4 + r) * 64 + colg * 4;
      float4 o;
      o.x = fmaxf(acc[r][0] + bch[colg * 4 + 0], 0.0f) * inv;
      o.y = fmaxf(acc[r][1] + bch[colg * 4 + 1], 0.0f) * inv;
      o.z = fmaxf(acc[r][2] + bch[colg * 4 + 2], 0.0f) * inv;
      o.w = fmaxf(acc[r][3] + bch[colg * 4 + 3], 0.0f) * inv;
      *(float4*)op = o;
    }
  }
}

extern "C" void kernel_launch(void* const* d_in, const int* in_sizes, int n_in,
                              void* d_out, int out_size, void* d_ws, size_t ws_size,
                              hipStream_t stream) {
  const float* inp   = (const float*)d_in[0];
  const float* ident = (const float*)d_in[1];
  const float* enh   = (const float*)d_in[2];
  const float* inh   = (const float*)d_in[3];
  const float* beta  = (const float*)d_in[4];
  const float* delta = (const float*)d_in[5];

  hipLaunchKernelGGL(front_k, dim3(61), dim3(256), 0, stream,
                     ident, enh, inh, beta, delta, d_ws);
  hipLaunchKernelGGL(batch_k, dim3(512), dim3(512), 0, stream,
                     inp, (const float*)d_ws, (float*)d_out);
}